// Round 10
// baseline (441.529 us; speedup 1.0000x reference)
//
#include <hip/hip_runtime.h>
#include <hip/hip_bf16.h>

// ---------------------------------------------------------------------------
// Attention block, N=8192 D=1024 (inputs fp32 or bf16, runtime-detected;
// output float32):
//   qkv = x @ Wqkv ; S = q k^T / 32 (causal) ; P = softmax(S) ; O = P v
//   out = O @ Wout + bout
// R17: 128x256 tiles / 512 threads / 8 waves (2m x 4n) for the three
// stall-bound MFMA kernels (R16 counters: MfmaUtil 26, occupancy 27, HBM 25
// -> latency-bound barrier drain, under-occupied). acc[4][4]/wave unchanged;
// A staged once per 256 cols (-25% global loads); MFMA per block-step 2x;
// LDS 48KB -> 3 blocks/CU x 8 waves = 24 waves/CU of TLP. Sync structure
// unchanged (2-buffer, stage-before-mma, __syncthreads - proven).
// k_qk_exp pairs causal tiles (I,2p),(I,2p+1): 1056 blocks, phantom half
// (odd rows) gives e=0 and its STORE is guarded (Jt<=I). k_pv unchanged.
// Keeps: XCD swizzles, 0-conflict swizzled LDS, fragment-major E, vectorized
// k_convert.
// ---------------------------------------------------------------------------

typedef __bf16 v8bf __attribute__((ext_vector_type(8)));
typedef float  v4f  __attribute__((ext_vector_type(4)));

struct __align__(8) S4 { short x, y, z, w; };

__device__ inline short f2bf(float f) {
  __hip_bfloat16 h = __float2bfloat16(f);
  return *reinterpret_cast<short*>(&h);
}
__device__ inline float bf2f(short s) {
  unsigned u = ((unsigned)(unsigned short)s) << 16;
  float f;
  __builtin_memcpy(&f, &u, 4);
  return f;
}

// ---- 512-thread staging (both-sides swizzle: LDS (row,pos) holds global
// (row, pos ^ ((row>>1)&3)); linear LDS dest, wave-uniform base). ----
// 128x32 bf16 tile: 512 chunks of 16B -> 1 load/thread.
__device__ inline void stageA512(const short* g0, int ldg, short* lds, int tid) {
  const int c = tid;
  const int row = c >> 2;
  const int pos = (c & 3) ^ ((row >> 1) & 3);
  const short* g = g0 + (size_t)row * ldg + pos * 8;
  short* l = lds + (tid >> 6) * 512;              // wave-uniform; HW adds lane*16B
  __builtin_amdgcn_global_load_lds(
      (__attribute__((address_space(1))) void*)(void*)g,
      (__attribute__((address_space(3))) void*)l, 16, 0, 0);
}
// 256x32 bf16 tile: 1024 chunks -> 2 loads/thread.
__device__ inline void stageB512(const short* g0, int ldg, short* lds, int tid) {
#pragma unroll
  for (int p = 0; p < 2; ++p) {
    const int c = p * 512 + tid;
    const int row = c >> 2;
    const int pos = (c & 3) ^ ((row >> 1) & 3);
    const short* g = g0 + (size_t)row * ldg + pos * 8;
    short* l = lds + p * 4096 + (tid >> 6) * 512;
    __builtin_amdgcn_global_load_lds(
        (__attribute__((address_space(1))) void*)(void*)g,
        (__attribute__((address_space(3))) void*)l, 16, 0, 0);
  }
}

// One BK=32 step: A 128 rows, B up to 256 rows (wn selects 64-row strip).
// 8 ds_read_b128 + 16 MFMA per wave. Read swizzle matches stage (row-based;
// (r16>>1)&3 is invariant to the wn*64/wm*64 offset).
__device__ inline void mma_step(const short* As, const short* Bs, v4f acc[4][4],
                                int lane, int wm, int wn) {
  const int qd = lane >> 4, r16 = lane & 15;
  const int sw = (qd ^ ((r16 >> 1) & 3)) * 8;
  const short* ab = As + (wm * 64 + r16) * 32 + sw;
  const short* bb = Bs + (wn * 64 + r16) * 32 + sw;
  v8bf a[4], b[4];
#pragma unroll
  for (int t = 0; t < 4; ++t) {
    a[t] = *(const v8bf*)(ab + t * 512);
    b[t] = *(const v8bf*)(bb + t * 512);
  }
#pragma unroll
  for (int mt = 0; mt < 4; ++mt)
#pragma unroll
    for (int nt = 0; nt < 4; ++nt)
      acc[mt][nt] = __builtin_amdgcn_mfma_f32_16x16x32_bf16(a[mt], b[nt], acc[mt][nt], 0, 0, 0);
}

#define ACC_INIT(acc)                              \
  _Pragma("unroll") for (int i_ = 0; i_ < 4; ++i_) \
  _Pragma("unroll") for (int j_ = 0; j_ < 4; ++j_) \
      acc[i_][j_] = (v4f){0.f, 0.f, 0.f, 0.f};

// ---------------------------------------------------------------------------
__global__ __launch_bounds__(256) void k_zerof(float* __restrict__ p, int n) {
  const int i = blockIdx.x * 256 + threadIdx.x;
  if (i < n) p[i] = 0.f;
}

// Input dtype detection: bf16 unit-normal shorts never have exponent >= 0xC0.
__global__ __launch_bounds__(256) void k_detect(const unsigned short* __restrict__ xs,
                                                int* __restrict__ flag) {
  __shared__ int cnt;
  if (threadIdx.x == 0) cnt = 0;
  __syncthreads();
  int local = 0;
  for (int i = threadIdx.x; i < 4096; i += 256) {
    const unsigned e = (xs[i] >> 7) & 0xFFu;
    if (e >= 0xC0u) ++local;
  }
  if (local) atomicAdd(&cnt, local);
  __syncthreads();
  if (threadIdx.x == 0) *flag = (cnt > 8) ? 1 : 0;
}

// Convert input (fp32 or bf16 per flag) to bf16 shorts. Vectorized (G13).
__global__ __launch_bounds__(256) void k_convert(const void* __restrict__ in,
                                                 short* __restrict__ out, int n,
                                                 const int* __restrict__ flag) {
  const int stride = gridDim.x * blockDim.x;
  const int i0 = blockIdx.x * blockDim.x + threadIdx.x;
  if (*flag != 0) {
    const float4* p = (const float4*)in;
    S4* o = (S4*)out;
    for (int v = i0; v < (n >> 2); v += stride) {
      const float4 f = p[v];
      S4 s;
      s.x = f2bf(f.x); s.y = f2bf(f.y); s.z = f2bf(f.z); s.w = f2bf(f.w);
      o[v] = s;
    }
  } else {
    const int4* p = (const int4*)in;
    int4* o = (int4*)out;
    for (int v = i0; v < (n >> 3); v += stride) o[v] = p[v];
  }
}

// Convert input (fp32 or bf16 per flag) to fp32.
__global__ __launch_bounds__(256) void k_to_f32(const void* __restrict__ in,
                                                float* __restrict__ out, int n,
                                                const int* __restrict__ flag) {
  const int stride = gridDim.x * blockDim.x;
  int i = blockIdx.x * blockDim.x + threadIdx.x;
  if (*flag != 0) {
    const float* p = (const float*)in;
    for (; i < n; i += stride) out[i] = p[i];
  } else {
    const short* p = (const short*)in;
    for (; i < n; i += stride) out[i] = bf2f(p[i]);
  }
}

// ---------------------------------------------------------------------------
// Fused convert + transpose: in [R][C] (fp32 or bf16 per flag) -> out bf16 [C][R]
__global__ __launch_bounds__(256) void k_convT(const void* __restrict__ in,
                                               short* __restrict__ out, int R, int C,
                                               const int* __restrict__ flag) {
  __shared__ short t[32][33];
  const int xx = threadIdx.x & 31, y0 = threadIdx.x >> 5;
  const int c0 = blockIdx.x * 32, r0 = blockIdx.y * 32;
  if (*flag != 0) {
    const float* p = (const float*)in;
#pragma unroll
    for (int i = 0; i < 4; ++i) {
      int r = y0 + i * 8;
      t[r][xx] = f2bf(p[(size_t)(r0 + r) * C + c0 + xx]);
    }
  } else {
    const short* p = (const short*)in;
#pragma unroll
    for (int i = 0; i < 4; ++i) {
      int r = y0 + i * 8;
      t[r][xx] = p[(size_t)(r0 + r) * C + c0 + xx];
    }
  }
  __syncthreads();
#pragma unroll
  for (int i = 0; i < 4; ++i) {
    int r = y0 + i * 8;
    out[(size_t)(c0 + r) * R + r0 + xx] = t[xx][r];
  }
}

// ---------------------------------------------------------------------------
// GEMM1: qkv = x[8192][1024] @ Wqkv -> q,k into qk[8192][2048]; v as vT[1024][8192]
// 128x256 tile, 512 threads, 8 waves (wm=wave>>2, wn=wave&3).
__global__ __launch_bounds__(512) void k_gemm_qkv(const short* __restrict__ x,
                                                  const short* __restrict__ wt,  // [3072][1024]
                                                  short* __restrict__ qk,
                                                  short* __restrict__ vT) {
  __shared__ short As[2][4096], Bs[2][8192];
  const int tid = threadIdx.x, lane = tid & 63, wave = tid >> 6;
  const int wm = wave >> 2, wn = wave & 3;
  // XCD swizzle: 768 blocks = 8 x 96; m-major within XCD (8 m x 12 n each).
  const int lin = (int)blockIdx.y * 64 + (int)blockIdx.x;
  const int swz = (lin & 7) * 96 + (lin >> 3);
  const int m0 = (swz / 12) * 128, n0 = (swz % 12) * 256;
  const short* srcA = x + (size_t)m0 * 1024;
  const short* srcB = wt + (size_t)n0 * 1024;
  v4f acc[4][4];
  ACC_INIT(acc)
  stageA512(srcA, 1024, As[0], tid);
  stageB512(srcB, 1024, Bs[0], tid);
  __syncthreads();
  for (int k0 = 0; k0 < 1024; k0 += 32) {
    const int cur = (k0 >> 5) & 1;
    if (k0 + 32 < 1024) {
      stageA512(srcA + k0 + 32, 1024, As[cur ^ 1], tid);
      stageB512(srcB + k0 + 32, 1024, Bs[cur ^ 1], tid);
    }
    mma_step(As[cur], Bs[cur], acc, lane, wm, wn);
    __syncthreads();
  }
  const int qd = lane >> 4, c16 = lane & 15;
#pragma unroll
  for (int mt = 0; mt < 4; ++mt) {
    const int rl = wm * 64 + mt * 16 + qd * 4;
#pragma unroll
    for (int nt = 0; nt < 4; ++nt) {
      const int cl = wn * 64 + nt * 16 + c16;   // 0..255
      const int n = n0 + cl;
      if (n < 2048) {  // q,k : row-major store
#pragma unroll
        for (int r = 0; r < 4; ++r)
          qk[(size_t)(m0 + rl + r) * 2048 + n] = f2bf(acc[mt][nt][r]);
      } else {  // v : transposed store, 4 consecutive tokens -> one 8B store
        S4 p;
        p.x = f2bf(acc[mt][nt][0]);
        p.y = f2bf(acc[mt][nt][1]);
        p.z = f2bf(acc[mt][nt][2]);
        p.w = f2bf(acc[mt][nt][3]);
        *reinterpret_cast<S4*>(vT + (size_t)(n - 2048) * 8192 + (m0 + rl)) = p;
      }
    }
  }
}

// ---------------------------------------------------------------------------
// QK^T + exp over a PAIR of causal tiles (I,J0),(I,J0+1), J0=2p; E packed
// lower-triangular in A-FRAGMENT-MAJOR layout for k_pv:
//   frag (fi, jj) at BLK = ((fi>>2)*4 + jj)*4 + (fi&3), offset BLK*512 + lane*8
// Pair index: row I=2m occupies b in [m^2+m, (m+1)^2); I=2m+1 in
// [(m+1)^2, (m+1)(m+2)). Phantom half (J0+1 > I): e=0, store GUARDED.
// Epilogue accumulates per-row sums of exp into l[8192] via atomicAdd.
__global__ __launch_bounds__(512) void k_qk_exp(const short* __restrict__ qk,
                                                short* __restrict__ E,
                                                float* __restrict__ l) {
  __shared__ short As[2][4096], Bs[2][8192];
  __shared__ float srow[128][4];
  const int tid = threadIdx.x, lane = tid & 63, wave = tid >> 6;
  const int wm = wave >> 2, wn = wave & 3;
  // XCD swizzle: 1056 = 8 x 132.
  const int b = ((int)blockIdx.x & 7) * 132 + ((int)blockIdx.x >> 3);
  int m = (int)((sqrtf(4.f * (float)b + 1.f) - 1.f) * 0.5f);
  while ((m + 1) * (m + 2) <= b) ++m;
  while (m * (m + 1) > b) --m;
  int I, p;
  if (b < (m + 1) * (m + 1)) { I = 2 * m;     p = b - m * (m + 1); }
  else                       { I = 2 * m + 1; p = b - (m + 1) * (m + 1); }
  const int J0 = 2 * p;
  const int m0 = I * 128, n0 = J0 * 128;     // 256 cols: tiles J0, J0+1
  const short* srcA = qk + (size_t)m0 * 2048;          // q rows
  const short* srcB = qk + 1024 + (size_t)n0 * 2048;   // k rows (256 of them)
  v4f acc[4][4];
  ACC_INIT(acc)
  stageA512(srcA, 2048, As[0], tid);
  stageB512(srcB, 2048, Bs[0], tid);
  __syncthreads();
  for (int k0 = 0; k0 < 1024; k0 += 32) {
    const int cur = (k0 >> 5) & 1;
    if (k0 + 32 < 1024) {
      stageA512(srcA + k0 + 32, 2048, As[cur ^ 1], tid);
      stageB512(srcB + k0 + 32, 2048, Bs[cur ^ 1], tid);
    }
    mma_step(As[cur], Bs[cur], acc, lane, wm, wn);
    __syncthreads();
  }
  const size_t triB = (size_t)I * (I + 1) / 2;
  const int qd = lane >> 4, c16 = lane & 15;
  float rp[4][4];
#pragma unroll
  for (int mt = 0; mt < 4; ++mt)
#pragma unroll
    for (int r = 0; r < 4; ++r) rp[mt][r] = 0.f;
#pragma unroll
  for (int mt = 0; mt < 4; ++mt) {
    const int rl = wm * 64 + mt * 16 + qd * 4;
#pragma unroll
    for (int nt = 0; nt < 4; ++nt) {
      const int cl = wn * 64 + nt * 16 + c16;   // 0..255
      const int Jt = J0 + (cl >> 7);            // tile of this column
      const int jloc = cl & 127;                // col within tile
      const int gj = n0 + cl;
      const bool valid = (Jt <= I);             // phantom guard (store only)
      const int jj = jloc >> 5, qdc = (jloc >> 3) & 3, jl = jloc & 7;
      short* dst = E + (triB + Jt) * 16384 + (((wm * 4 + jj) * 4 + mt) * 512) + qdc * 128 + jl;
#pragma unroll
      for (int r = 0; r < 4; ++r) {
        const int gi = m0 + rl + r;
        const float s = fminf(acc[mt][nt][r] * 0.03125f, 60.f);  // NaN-proof
        const float e = (gj > gi) ? 0.f : __expf(s);
        if (valid) dst[(qd * 4 + r) * 8] = f2bf(e);   // r16 = qd*4+r
        rp[mt][r] += e;                                // phantom adds 0
      }
    }
  }
#pragma unroll
  for (int mt = 0; mt < 4; ++mt)
#pragma unroll
    for (int r = 0; r < 4; ++r) {
      float v = rp[mt][r];
      v += __shfl_xor(v, 1);
      v += __shfl_xor(v, 2);
      v += __shfl_xor(v, 4);
      v += __shfl_xor(v, 8);
      rp[mt][r] = v;
    }
  if ((lane & 15) == 0) {
#pragma unroll
    for (int mt = 0; mt < 4; ++mt)
#pragma unroll
      for (int r = 0; r < 4; ++r)
        srow[wm * 64 + mt * 16 + qd * 4 + r][wn] = rp[mt][r];
  }
  __syncthreads();
  if (tid < 128)
    atomicAdd(&l[m0 + tid], (srow[tid][0] + srow[tid][1]) + (srow[tid][2] + srow[tid][3]));
}

// ---------------------------------------------------------------------------
// PV: attn = (E @ v) / l.  Tile 128x128; block does tile-rows I=bx and 63-bx
// (65 J-tiles total -> perfect balance). 512 threads, 8 waves of 16 rows
// each (fi = wave): zero-redundancy E fragment loads (4KB/wave/J), 2
// waves/SIMD. V [128][128] double-buffered in LDS via global_load_lds,
// XOR swizzle kc^=row&15 both sides. Prefetch-before-compute, __syncthreads
// per J (proven R12 structure).
__device__ __forceinline__ void pv_loadA8(v8bf a[4], const short* __restrict__ Et,
                                          int wave, int lane) {
  const int wm_ = wave >> 2, mt_ = wave & 3;
#pragma unroll
  for (int jj = 0; jj < 4; ++jj) {
    const int BLK = (wm_ * 4 + jj) * 4 + mt_;
    a[jj] = *(const v8bf*)(Et + BLK * 512 + lane * 8);
  }
}

// Stage 128x128-short V tile (rows stride 8192) into LDS, swizzled. 4 loads/thread.
__device__ __forceinline__ void pv_stageV8(const short* __restrict__ vbJ,
                                           short* __restrict__ lds, int tid) {
#pragma unroll
  for (int p = 0; p < 4; ++p) {
    const int c = p * 512 + tid;                 // chunk id 0..2047
    const int row = c >> 4;                      // 0..127
    const int kc = (c & 15) ^ (row & 15);        // swizzled source chunk
    const short* g = vbJ + (size_t)row * 8192 + kc * 8;
    short* lp = lds + (p * 512 + (tid >> 6) * 64) * 8;  // wave-uniform; HW adds lane*16B
    __builtin_amdgcn_global_load_lds(
        (__attribute__((address_space(1))) void*)(void*)g,
        (__attribute__((address_space(3))) void*)lp, 16, 0, 0);
  }
}

__device__ __forceinline__ void pv_compute8(const v8bf a[4], const short* __restrict__ Vbuf,
                                            v4f acc[8], int qd, int r16) {
#pragma unroll
  for (int jj = 0; jj < 4; ++jj) {
    v8bf b[8];
#pragma unroll
    for (int u = 0; u < 8; ++u) {
      const int row = u * 16 + r16;
      const int kc = (jj * 4 + qd) ^ r16;        // row&15 == r16
      b[u] = *(const v8bf*)(Vbuf + row * 128 + kc * 8);
    }
#pragma unroll
    for (int u = 0; u < 8; ++u)
      acc[u] = __builtin_amdgcn_mfma_f32_16x16x32_bf16(a[jj], b[u], acc[u], 0, 0, 0);
  }
}

__global__ __launch_bounds__(512) void k_pv(const short* __restrict__ E,
                                            const short* __restrict__ vT,  // [1024][8192]
                                            const float* __restrict__ l,
                                            short* __restrict__ attn) {
  __shared__ short Vb[2][16384];  // 2 x 32KB double-buffered V tile [128][128]
  const int tid = threadIdx.x, lane = tid & 63, wave = tid >> 6;  // wave 0..7
  const int bx = (int)blockIdx.x;        // 0..31
  const int n0 = (int)blockIdx.y * 128;  // 0..7
  const int qd = lane >> 4, r16 = lane & 15;
  const short* vb = vT + (size_t)n0 * 8192;
  for (int half = 0; half < 2; ++half) {
    const int I = half ? 63 - bx : bx;
    const int m0 = I * 128;
    const short* Erow = E + (size_t)(I * (I + 1) / 2) * 16384;
    v4f acc[8];
#pragma unroll
    for (int u = 0; u < 8; ++u) acc[u] = (v4f){0.f, 0.f, 0.f, 0.f};
    v8bf aA[4], aB[4];
    __syncthreads();                      // prev half's Vb readers done
    pv_stageV8(vb, Vb[0], tid);
    pv_loadA8(aA, Erow, wave, lane);
    __syncthreads();                      // Vb[0] staged (vmcnt drained)
    for (int J = 0;; J += 2) {
      if (J + 1 <= I) {                   // prefetch J+1 (LDS buf 1, then regs)
        pv_stageV8(vb + (J + 1) * 128, Vb[1], tid);
        pv_loadA8(aB, Erow + (size_t)(J + 1) * 16384, wave, lane);
      }
      pv_compute8(aA, Vb[0], acc, qd, r16);
      if (J + 1 > I) break;
      __syncthreads();                    // Vb[1] ready; Vb[0] readers done
      if (J + 2 <= I) {                   // prefetch J+2 (LDS buf 0, then regs)
        pv_stageV8(vb + (J + 2) * 128, Vb[0], tid);
        pv_loadA8(aA, Erow + (size_t)(J + 2) * 16384, wave, lane);
      }
      pv_compute8(aB, Vb[1], acc, qd, r16);
      if (J + 2 > I) break;
      __syncthreads();                    // Vb[0] ready; Vb[1] readers done
    }
    const int rbase = wave * 16 + qd * 4;
    float inv[4];
#pragma unroll
    for (int r = 0; r < 4; ++r) inv[r] = 1.0f / fmaxf(l[m0 + rbase + r], 1e-30f);
#pragma unroll
    for (int u = 0; u < 8; ++u) {
#pragma unroll
      for (int r = 0; r < 4; ++r)
        attn[(size_t)(m0 + rbase + r) * 1024 + n0 + u * 16 + r16] = f2bf(acc[u][r] * inv[r]);
    }
  }
}

// ---------------------------------------------------------------------------
// GEMM2: out = attn[8192][1024] @ Wout + bout  -- FLOAT32 output
// 128x256 tile, 512 threads, 8 waves.
__global__ __launch_bounds__(512) void k_gemm_out(const short* __restrict__ attn,
                                                  const short* __restrict__ wt,  // [1024][1024] = Wout^T
                                                  const float* __restrict__ bout,
                                                  float* __restrict__ out) {
  __shared__ short As[2][4096], Bs[2][8192];
  const int tid = threadIdx.x, lane = tid & 63, wave = tid >> 6;
  const int wm = wave >> 2, wn = wave & 3;
  // XCD swizzle: 256 blocks = 8 x 32; each XCD 8 m x 4 n.
  const int lin = (int)blockIdx.y * 64 + (int)blockIdx.x;
  const int swz = (lin & 7) * 32 + (lin >> 3);
  const int m0 = (swz >> 2) * 128, n0 = (swz & 3) * 256;
  const short* srcA = attn + (size_t)m0 * 1024;
  const short* srcB = wt + (size_t)n0 * 1024;
  v4f acc[4][4];
  ACC_INIT(acc)
  stageA512(srcA, 1024, As[0], tid);
  stageB512(srcB, 1024, Bs[0], tid);
  __syncthreads();
  for (int k0 = 0; k0 < 1024; k0 += 32) {
    const int cur = (k0 >> 5) & 1;
    if (k0 + 32 < 1024) {
      stageA512(srcA + k0 + 32, 1024, As[cur ^ 1], tid);
      stageB512(srcB + k0 + 32, 1024, Bs[cur ^ 1], tid);
    }
    mma_step(As[cur], Bs[cur], acc, lane, wm, wn);
    __syncthreads();
  }
  const int qd = lane >> 4, c16 = lane & 15;
#pragma unroll
  for (int mt = 0; mt < 4; ++mt) {
    const int rl = wm * 64 + mt * 16 + qd * 4;
#pragma unroll
    for (int nt = 0; nt < 4; ++nt) {
      const int cl = wn * 64 + nt * 16 + c16;
      const float bias = bout[n0 + cl];
#pragma unroll
      for (int r = 0; r < 4; ++r)
        out[(size_t)(m0 + rl + r) * 1024 + n0 + cl] = acc[mt][nt][r] + bias;
    }
  }
}

// ---------------------------------------------------------------------------
extern "C" void kernel_launch(void* const* d_in, const int* in_sizes, int n_in,
                              void* d_out, int out_size, void* d_ws, size_t ws_size,
                              hipStream_t stream) {
  (void)out_size; (void)ws_size;
  const void *x = d_in[0], *Wqkv = d_in[1], *Wout = d_in[2], *bout = d_in[3];
  for (int i = 0; i < n_in; ++i) {
    switch (in_sizes[i]) {
      case 8192 * 1024: x = d_in[i]; break;
      case 1024 * 3072: Wqkv = d_in[i]; break;
      case 1024 * 1024: Wout = d_in[i]; break;
      case 1024:        bout = d_in[i]; break;
      default: break;
    }
  }

  char* ws = (char*)d_ws;
  short* qk    = (short*)(ws);                // 8192x2048 bf16 (q | k)   33.55 MB
  short* vT    = (short*)(ws + 33554432);     // 1024x8192 bf16           16.78 MB
  short* E     = (short*)(ws + 50331648);     // 2080 tiles of 128x128    68.16 MB
  short* xb    = (short*)(ws + 118489088);    // 8192x1024 bf16           16.78 MB
  short* attn  = xb;                          //   xb dead after GEMM1
  short* WqT   = (short*)(ws + 135266304);    // 3072x1024 bf16            6.29 MB
  short* WoT   = (short*)(ws + 141557760);    // 1024x1024 bf16            2.10 MB
  float* boutf = (float*)(ws + 143654912);    // 1024 fp32
  float* lsum  = (float*)(ws + 143659008);    // 8192 fp32 softmax denominators
  int*   flag  = (int*)  (ws + 143691776);    // dtype flag

  k_detect<<<1, 256, 0, stream>>>((const unsigned short*)x, flag);
  k_zerof<<<32, 256, 0, stream>>>(lsum, 8192);
  k_convert<<<1024, 256, 0, stream>>>(x, xb, 8192 * 1024, flag);
  k_to_f32<<<1, 256, 0, stream>>>(bout, boutf, 1024, flag);
  k_convT<<<dim3(96, 32), 256, 0, stream>>>(Wqkv, WqT, 1024, 3072, flag);
  k_convT<<<dim3(32, 32), 256, 0, stream>>>(Wout, WoT, 1024, 1024, flag);
  k_gemm_qkv<<<dim3(64, 12), 512, 0, stream>>>(xb, WqT, qk, vT);
  k_qk_exp<<<dim3(1056), 512, 0, stream>>>(qk, E, lsum);
  k_pv<<<dim3(32, 8), 512, 0, stream>>>(E, vT, lsum, attn);
  k_gemm_out<<<dim3(64, 4), 512, 0, stream>>>(attn, WoT, boutf, (float*)d_out);
}

// Round 11
// 393.023 us; speedup vs baseline: 1.1234x; 1.1234x over previous
//
#include <hip/hip_runtime.h>
#include <hip/hip_bf16.h>

// ---------------------------------------------------------------------------
// Attention block, N=8192 D=1024 (inputs fp32 or bf16, runtime-detected;
// output float32):
//   qkv = x @ Wqkv ; S = q k^T / 32 (causal) ; P = softmax(S) ; O = P v
//   out = O @ Wout + bout
// R18: full revert to R16 (best verified, 404.9us) EXCEPT k_pv, which was
// LDS-PIPE-bound: old slicing (8 waves x 16rows x 128cols) made every wave
// re-read the whole shared V tile -> 32 ds_read_b128 per 32 MFMA per wave
// (256KB LDS/CU/J = ~3072cy vs ~1030cy MFMA). New slicing 4i x 2d: each
// wave owns 32 E-rows x 64 V-cols -> V reads halve (16 per 32 MFMA), E
// fragment loads double (global, coalesced, cheap; absorbed by L1/L2).
// Per-CU per-J: LDS 1536cy ~ TA 1536cy ~ MFMA 1033cy -> balanced.
// Keeps: 2-buffer stage-before-mma __syncthreads GEMMs, XCD swizzles,
// 0-conflict swizzled LDS, fragment-major E, vectorized k_convert.
// ---------------------------------------------------------------------------

typedef __bf16 v8bf __attribute__((ext_vector_type(8)));
typedef float  v4f  __attribute__((ext_vector_type(4)));

struct __align__(8) S4 { short x, y, z, w; };

__device__ inline short f2bf(float f) {
  __hip_bfloat16 h = __float2bfloat16(f);
  return *reinterpret_cast<short*>(&h);
}
__device__ inline float bf2f(short s) {
  unsigned u = ((unsigned)(unsigned short)s) << 16;
  float f;
  __builtin_memcpy(&f, &u, 4);
  return f;
}

// Async stage of a 128x32 bf16 tile (row-major, ldg) into LDS [128][32].
// global_load_lds width=16: LDS dest is wave-uniform base + lane*16B (linear).
// Bank-swizzle applied on the GLOBAL source chunk (both-sides rule):
// LDS (row,pos) holds global (row, pos ^ ((row>>1)&3)).
__device__ inline void stage_tile(const short* gbase, int ldg, short* lds, int tid) {
#pragma unroll
  for (int p = 0; p < 2; ++p) {
    const int c = p * 256 + tid;                    // 16B-chunk id; lane order matches dest
    const int pos = (c & 3) ^ ((c >> 3) & 3);       // swizzled source chunk within row
    const short* g = gbase + (size_t)(c >> 2) * ldg + pos * 8;
    short* l = lds + p * 2048 + (tid >> 6) * 512;   // wave-uniform; HW adds lane*16B
    __builtin_amdgcn_global_load_lds(
        (__attribute__((address_space(1))) void*)(void*)g,
        (__attribute__((address_space(3))) void*)l, 16, 0, 0);
  }
}

// One BK=32 step for 128x128 tiles: 8 ds_read_b128 + 16 MFMA.
__device__ inline void mma_step(const short* As, const short* Bs, v4f acc[4][4],
                                int lane, int wm, int wn) {
  const int qd = lane >> 4, r16 = lane & 15;
  const int sw = (qd ^ ((r16 >> 1) & 3)) * 8;
  const short* ab = As + (wm * 64 + r16) * 32 + sw;
  const short* bb = Bs + (wn * 64 + r16) * 32 + sw;
  v8bf a[4], b[4];
#pragma unroll
  for (int t = 0; t < 4; ++t) {
    a[t] = *(const v8bf*)(ab + t * 512);
    b[t] = *(const v8bf*)(bb + t * 512);
  }
#pragma unroll
  for (int mt = 0; mt < 4; ++mt)
#pragma unroll
    for (int nt = 0; nt < 4; ++nt)
      acc[mt][nt] = __builtin_amdgcn_mfma_f32_16x16x32_bf16(a[mt], b[nt], acc[mt][nt], 0, 0, 0);
}

#define ACC_INIT(acc)                              \
  _Pragma("unroll") for (int i_ = 0; i_ < 4; ++i_) \
  _Pragma("unroll") for (int j_ = 0; j_ < 4; ++j_) \
      acc[i_][j_] = (v4f){0.f, 0.f, 0.f, 0.f};

// ---------------------------------------------------------------------------
__global__ __launch_bounds__(256) void k_zerof(float* __restrict__ p, int n) {
  const int i = blockIdx.x * 256 + threadIdx.x;
  if (i < n) p[i] = 0.f;
}

// Input dtype detection: bf16 unit-normal shorts never have exponent >= 0xC0.
__global__ __launch_bounds__(256) void k_detect(const unsigned short* __restrict__ xs,
                                                int* __restrict__ flag) {
  __shared__ int cnt;
  if (threadIdx.x == 0) cnt = 0;
  __syncthreads();
  int local = 0;
  for (int i = threadIdx.x; i < 4096; i += 256) {
    const unsigned e = (xs[i] >> 7) & 0xFFu;
    if (e >= 0xC0u) ++local;
  }
  if (local) atomicAdd(&cnt, local);
  __syncthreads();
  if (threadIdx.x == 0) *flag = (cnt > 8) ? 1 : 0;
}

// Convert input (fp32 or bf16 per flag) to bf16 shorts. Vectorized (G13).
__global__ __launch_bounds__(256) void k_convert(const void* __restrict__ in,
                                                 short* __restrict__ out, int n,
                                                 const int* __restrict__ flag) {
  const int stride = gridDim.x * blockDim.x;
  const int i0 = blockIdx.x * blockDim.x + threadIdx.x;
  if (*flag != 0) {
    const float4* p = (const float4*)in;
    S4* o = (S4*)out;
    for (int v = i0; v < (n >> 2); v += stride) {
      const float4 f = p[v];
      S4 s;
      s.x = f2bf(f.x); s.y = f2bf(f.y); s.z = f2bf(f.z); s.w = f2bf(f.w);
      o[v] = s;
    }
  } else {
    const int4* p = (const int4*)in;
    int4* o = (int4*)out;
    for (int v = i0; v < (n >> 3); v += stride) o[v] = p[v];
  }
}

// Convert input (fp32 or bf16 per flag) to fp32.
__global__ __launch_bounds__(256) void k_to_f32(const void* __restrict__ in,
                                                float* __restrict__ out, int n,
                                                const int* __restrict__ flag) {
  const int stride = gridDim.x * blockDim.x;
  int i = blockIdx.x * blockDim.x + threadIdx.x;
  if (*flag != 0) {
    const float* p = (const float*)in;
    for (; i < n; i += stride) out[i] = p[i];
  } else {
    const short* p = (const short*)in;
    for (; i < n; i += stride) out[i] = bf2f(p[i]);
  }
}

// ---------------------------------------------------------------------------
// Fused convert + transpose: in [R][C] (fp32 or bf16 per flag) -> out bf16 [C][R]
__global__ __launch_bounds__(256) void k_convT(const void* __restrict__ in,
                                               short* __restrict__ out, int R, int C,
                                               const int* __restrict__ flag) {
  __shared__ short t[32][33];
  const int xx = threadIdx.x & 31, y0 = threadIdx.x >> 5;
  const int c0 = blockIdx.x * 32, r0 = blockIdx.y * 32;
  if (*flag != 0) {
    const float* p = (const float*)in;
#pragma unroll
    for (int i = 0; i < 4; ++i) {
      int r = y0 + i * 8;
      t[r][xx] = f2bf(p[(size_t)(r0 + r) * C + c0 + xx]);
    }
  } else {
    const short* p = (const short*)in;
#pragma unroll
    for (int i = 0; i < 4; ++i) {
      int r = y0 + i * 8;
      t[r][xx] = p[(size_t)(r0 + r) * C + c0 + xx];
    }
  }
  __syncthreads();
#pragma unroll
  for (int i = 0; i < 4; ++i) {
    int r = y0 + i * 8;
    out[(size_t)(c0 + r) * R + r0 + xx] = t[xx][r];
  }
}

// ---------------------------------------------------------------------------
// GEMM1: qkv = x[8192][1024] @ Wqkv -> q,k into qk[8192][2048]; v written as vT[1024][8192]
__global__ __launch_bounds__(256) void k_gemm_qkv(const short* __restrict__ x,
                                                  const short* __restrict__ wt,  // [3072][1024]
                                                  short* __restrict__ qk,
                                                  short* __restrict__ vT) {
  __shared__ short As[2][4096], Bs[2][4096];
  const int tid = threadIdx.x, lane = tid & 63, wave = tid >> 6;
  const int wm = wave >> 1, wn = wave & 1;
  // XCD swizzle: 1536 blocks = 8 x 192; each XCD gets 8 m-tiles x 24 n-tiles.
  const int lin = (int)blockIdx.y * 64 + (int)blockIdx.x;
  const int swz = (lin & 7) * 192 + (lin >> 3);
  const int m0 = (swz / 24) * 128, n0 = (swz % 24) * 128;
  const short* srcA = x + (size_t)m0 * 1024;
  const short* srcB = wt + (size_t)n0 * 1024;
  v4f acc[4][4];
  ACC_INIT(acc)
  stage_tile(srcA, 1024, As[0], tid);
  stage_tile(srcB, 1024, Bs[0], tid);
  __syncthreads();
  for (int k0 = 0; k0 < 1024; k0 += 32) {
    const int cur = (k0 >> 5) & 1;
    if (k0 + 32 < 1024) {
      stage_tile(srcA + k0 + 32, 1024, As[cur ^ 1], tid);
      stage_tile(srcB + k0 + 32, 1024, Bs[cur ^ 1], tid);
    }
    mma_step(As[cur], Bs[cur], acc, lane, wm, wn);
    __syncthreads();
  }
  const int qd = lane >> 4, c16 = lane & 15;
#pragma unroll
  for (int mt = 0; mt < 4; ++mt) {
    const int rl = wm * 64 + mt * 16 + qd * 4;
#pragma unroll
    for (int nt = 0; nt < 4; ++nt) {
      const int cl = wn * 64 + nt * 16 + c16;
      const int n = n0 + cl;
      if (n < 2048) {  // q,k : row-major store
#pragma unroll
        for (int r = 0; r < 4; ++r)
          qk[(size_t)(m0 + rl + r) * 2048 + n] = f2bf(acc[mt][nt][r]);
      } else {  // v : transposed store, 4 consecutive tokens -> one 8B store
        S4 p;
        p.x = f2bf(acc[mt][nt][0]);
        p.y = f2bf(acc[mt][nt][1]);
        p.z = f2bf(acc[mt][nt][2]);
        p.w = f2bf(acc[mt][nt][3]);
        *reinterpret_cast<S4*>(vT + (size_t)(n - 2048) * 8192 + (m0 + rl)) = p;
      }
    }
  }
}

// ---------------------------------------------------------------------------
// QK^T + exp: causal tile (I,J), J<=I; E packed lower-triangular, stored in
// A-FRAGMENT-MAJOR layout for k_pv:
//   frag (fi, jj) at BLK = ((fi>>2)*4 + jj)*4 + (fi&3), offset BLK*512 + lane*8
// Epilogue accumulates per-row sums of exp into l[8192] via atomicAdd.
__global__ __launch_bounds__(256) void k_qk_exp(const short* __restrict__ qk,
                                                short* __restrict__ E,
                                                float* __restrict__ l) {
  __shared__ short As[2][4096], Bs[2][4096];
  __shared__ float srow[128][2];
  const int tid = threadIdx.x, lane = tid & 63, wave = tid >> 6;
  const int wm = wave >> 1, wn = wave & 1;
  // XCD swizzle: 2080 = 8 x 260; consecutive b (same/neighbor I) share q/k
  // panels within one XCD's L2.
  const int b = ((int)blockIdx.x & 7) * 260 + ((int)blockIdx.x >> 3);
  int I = (int)((sqrtf(8.f * (float)b + 1.f) - 1.f) * 0.5f);
  while ((I + 1) * (I + 2) / 2 <= b) ++I;
  while (I * (I + 1) / 2 > b) --I;
  const int J = b - I * (I + 1) / 2;
  const int m0 = I * 128, n0 = J * 128;
  const short* srcA = qk + (size_t)m0 * 2048;          // q rows
  const short* srcB = qk + 1024 + (size_t)n0 * 2048;   // k rows (B^T)
  v4f acc[4][4];
  ACC_INIT(acc)
  stage_tile(srcA, 2048, As[0], tid);
  stage_tile(srcB, 2048, Bs[0], tid);
  __syncthreads();
  for (int k0 = 0; k0 < 1024; k0 += 32) {
    const int cur = (k0 >> 5) & 1;
    if (k0 + 32 < 1024) {
      stage_tile(srcA + k0 + 32, 2048, As[cur ^ 1], tid);
      stage_tile(srcB + k0 + 32, 2048, Bs[cur ^ 1], tid);
    }
    mma_step(As[cur], Bs[cur], acc, lane, wm, wn);
    __syncthreads();
  }
  short* tb = E + (size_t)(I * (I + 1) / 2 + J) * 16384;
  const int qd = lane >> 4, c16 = lane & 15;
  float rp[4][4];
#pragma unroll
  for (int mt = 0; mt < 4; ++mt)
#pragma unroll
    for (int r = 0; r < 4; ++r) rp[mt][r] = 0.f;
#pragma unroll
  for (int mt = 0; mt < 4; ++mt) {
    const int rl = wm * 64 + mt * 16 + qd * 4;
#pragma unroll
    for (int nt = 0; nt < 4; ++nt) {
      const int cl = wn * 64 + nt * 16 + c16;   // local j within tile
      const int gj = n0 + cl;
      // A-fragment-major address pieces (jl varies with c16 only):
      const int jj = cl >> 5, qdc = (cl >> 3) & 3, jl = cl & 7;
      short* dst = tb + (((wm * 4 + jj) * 4 + mt) * 512) + qdc * 128 + jl;
#pragma unroll
      for (int r = 0; r < 4; ++r) {
        const int gi = m0 + rl + r;
        const float s = fminf(acc[mt][nt][r] * 0.03125f, 60.f);  // NaN-proof
        const float e = (gj > gi) ? 0.f : __expf(s);
        dst[(qd * 4 + r) * 8] = f2bf(e);   // r16 = qd*4+r
        rp[mt][r] += e;
      }
    }
  }
#pragma unroll
  for (int mt = 0; mt < 4; ++mt)
#pragma unroll
    for (int r = 0; r < 4; ++r) {
      float v = rp[mt][r];
      v += __shfl_xor(v, 1);
      v += __shfl_xor(v, 2);
      v += __shfl_xor(v, 4);
      v += __shfl_xor(v, 8);
      rp[mt][r] = v;
    }
  if ((lane & 15) == 0) {
#pragma unroll
    for (int mt = 0; mt < 4; ++mt)
#pragma unroll
      for (int r = 0; r < 4; ++r)
        srow[wm * 64 + mt * 16 + qd * 4 + r][wn] = rp[mt][r];
  }
  __syncthreads();
  if (tid < 128) atomicAdd(&l[m0 + tid], srow[tid][0] + srow[tid][1]);
}

// ---------------------------------------------------------------------------
// PV: attn = (E @ v) / l.  Tile 128x128; block does tile-rows I=bx and 63-bx
// (65 J-tiles total -> perfect balance). 512 threads, 8 waves re-sliced
// R18: 4i x 2d -> wave owns 32 E-rows (i-frags 2(w>>1), 2(w>>1)+1) x 64
// V-cols (d-half w&1). V LDS reads per wave per J: 32 -> 16 for the same
// 32 MFMA (LDS-pipe was the bound); E fragment loads 4 -> 8 (global,
// coalesced; d-half pair shares them via L1/L2). V [128][128] double-
// buffered via global_load_lds, XOR swizzle kc^=row&15 both sides.
// Prefetch-before-compute, __syncthreads per J (proven structure).
__device__ __forceinline__ void pv_loadA2(v8bf a[2][4], const short* __restrict__ Et,
                                          int fi0, int lane) {
#pragma unroll
  for (int f = 0; f < 2; ++f) {
    const int fi = fi0 + f;
    const int wm_ = fi >> 2, mt_ = fi & 3;
#pragma unroll
    for (int jj = 0; jj < 4; ++jj) {
      const int BLK = (wm_ * 4 + jj) * 4 + mt_;
      a[f][jj] = *(const v8bf*)(Et + BLK * 512 + lane * 8);
    }
  }
}

// Stage 128x128-short V tile (rows stride 8192) into LDS, swizzled. 4 loads/thread.
__device__ __forceinline__ void pv_stageV8(const short* __restrict__ vbJ,
                                           short* __restrict__ lds, int tid) {
#pragma unroll
  for (int p = 0; p < 4; ++p) {
    const int c = p * 512 + tid;                 // chunk id 0..2047
    const int row = c >> 4;                      // 0..127
    const int kc = (c & 15) ^ (row & 15);        // swizzled source chunk
    const short* g = vbJ + (size_t)row * 8192 + kc * 8;
    short* lp = lds + (p * 512 + (tid >> 6) * 64) * 8;  // wave-uniform; HW adds lane*16B
    __builtin_amdgcn_global_load_lds(
        (__attribute__((address_space(1))) void*)(void*)g,
        (__attribute__((address_space(3))) void*)lp, 16, 0, 0);
  }
}

__device__ __forceinline__ void pv_compute2(const v8bf a[2][4], const short* __restrict__ Vbuf,
                                            v4f acc[2][4], int dh, int qd, int r16) {
#pragma unroll
  for (int jj = 0; jj < 4; ++jj) {
    v8bf b[4];
#pragma unroll
    for (int u = 0; u < 4; ++u) {
      const int row = dh * 64 + u * 16 + r16;
      const int kc = (jj * 4 + qd) ^ r16;        // row&15 == r16
      b[u] = *(const v8bf*)(Vbuf + row * 128 + kc * 8);
    }
#pragma unroll
    for (int f = 0; f < 2; ++f)
#pragma unroll
      for (int u = 0; u < 4; ++u)
        acc[f][u] = __builtin_amdgcn_mfma_f32_16x16x32_bf16(a[f][jj], b[u], acc[f][u], 0, 0, 0);
  }
}

__global__ __launch_bounds__(512) void k_pv(const short* __restrict__ E,
                                            const short* __restrict__ vT,  // [1024][8192]
                                            const float* __restrict__ l,
                                            short* __restrict__ attn) {
  __shared__ short Vb[2][16384];  // 2 x 32KB double-buffered V tile [128][128]
  const int tid = threadIdx.x, lane = tid & 63, wave = tid >> 6;  // wave 0..7
  const int bx = (int)blockIdx.x;        // 0..31
  const int n0 = (int)blockIdx.y * 128;  // 0..7
  const int qd = lane >> 4, r16 = lane & 15;
  const int fi0 = (wave >> 1) * 2;       // i-frag pair owned by this wave
  const int dh = wave & 1;               // d-half owned by this wave
  const short* vb = vT + (size_t)n0 * 8192;
  for (int half = 0; half < 2; ++half) {
    const int I = half ? 63 - bx : bx;
    const int m0 = I * 128;
    const short* Erow = E + (size_t)(I * (I + 1) / 2) * 16384;
    v4f acc[2][4];
#pragma unroll
    for (int f = 0; f < 2; ++f)
#pragma unroll
      for (int u = 0; u < 4; ++u) acc[f][u] = (v4f){0.f, 0.f, 0.f, 0.f};
    v8bf aA[2][4], aB[2][4];
    __syncthreads();                      // prev half's Vb readers done
    pv_stageV8(vb, Vb[0], tid);
    pv_loadA2(aA, Erow, fi0, lane);
    __syncthreads();                      // Vb[0] staged (vmcnt drained)
    for (int J = 0;; J += 2) {
      if (J + 1 <= I) {                   // prefetch J+1 (LDS buf 1, then regs)
        pv_stageV8(vb + (J + 1) * 128, Vb[1], tid);
        pv_loadA2(aB, Erow + (size_t)(J + 1) * 16384, fi0, lane);
      }
      pv_compute2(aA, Vb[0], acc, dh, qd, r16);
      if (J + 1 > I) break;
      __syncthreads();                    // Vb[1] ready; Vb[0] readers done
      if (J + 2 <= I) {                   // prefetch J+2 (LDS buf 0, then regs)
        pv_stageV8(vb + (J + 2) * 128, Vb[0], tid);
        pv_loadA2(aA, Erow + (size_t)(J + 2) * 16384, fi0, lane);
      }
      pv_compute2(aB, Vb[1], acc, dh, qd, r16);
      if (J + 2 > I) break;
      __syncthreads();                    // Vb[0] ready; Vb[1] readers done
    }
#pragma unroll
    for (int f = 0; f < 2; ++f) {
      const int rbase = (fi0 + f) * 16 + qd * 4;
      float inv[4];
#pragma unroll
      for (int r = 0; r < 4; ++r) inv[r] = 1.0f / fmaxf(l[m0 + rbase + r], 1e-30f);
#pragma unroll
      for (int u = 0; u < 4; ++u) {
        const int col = n0 + dh * 64 + u * 16 + r16;
#pragma unroll
        for (int r = 0; r < 4; ++r)
          attn[(size_t)(m0 + rbase + r) * 1024 + col] = f2bf(acc[f][u][r] * inv[r]);
      }
    }
  }
}

// ---------------------------------------------------------------------------
// GEMM2: out = attn[8192][1024] @ Wout + bout  -- FLOAT32 output
__global__ __launch_bounds__(256) void k_gemm_out(const short* __restrict__ attn,
                                                  const short* __restrict__ wt,  // [1024][1024] = Wout^T
                                                  const float* __restrict__ bout,
                                                  float* __restrict__ out) {
  __shared__ short As[2][4096], Bs[2][4096];
  const int tid = threadIdx.x, lane = tid & 63, wave = tid >> 6;
  const int wm = wave >> 1, wn = wave & 1;
  // XCD swizzle: 512 blocks = 8 x 64; each XCD 8 m-tiles x 8 n-tiles.
  const int lin = (int)blockIdx.y * 64 + (int)blockIdx.x;
  const int swz = (lin & 7) * 64 + (lin >> 3);
  const int m0 = (swz >> 3) * 128, n0 = (swz & 7) * 128;
  const short* srcA = attn + (size_t)m0 * 1024;
  const short* srcB = wt + (size_t)n0 * 1024;
  v4f acc[4][4];
  ACC_INIT(acc)
  stage_tile(srcA, 1024, As[0], tid);
  stage_tile(srcB, 1024, Bs[0], tid);
  __syncthreads();
  for (int k0 = 0; k0 < 1024; k0 += 32) {
    const int cur = (k0 >> 5) & 1;
    if (k0 + 32 < 1024) {
      stage_tile(srcA + k0 + 32, 1024, As[cur ^ 1], tid);
      stage_tile(srcB + k0 + 32, 1024, Bs[cur ^ 1], tid);
    }
    mma_step(As[cur], Bs[cur], acc, lane, wm, wn);
    __syncthreads();
  }
  const int qd = lane >> 4, c16 = lane & 15;
#pragma unroll
  for (int mt = 0; mt < 4; ++mt) {
    const int rl = wm * 64 + mt * 16 + qd * 4;
#pragma unroll
    for (int nt = 0; nt < 4; ++nt) {
      const int cl = wn * 64 + nt * 16 + c16;
      const float bias = bout[n0 + cl];
#pragma unroll
      for (int r = 0; r < 4; ++r)
        out[(size_t)(m0 + rl + r) * 1024 + n0 + cl] = acc[mt][nt][r] + bias;
    }
  }
}

// ---------------------------------------------------------------------------
extern "C" void kernel_launch(void* const* d_in, const int* in_sizes, int n_in,
                              void* d_out, int out_size, void* d_ws, size_t ws_size,
                              hipStream_t stream) {
  (void)out_size; (void)ws_size;
  const void *x = d_in[0], *Wqkv = d_in[1], *Wout = d_in[2], *bout = d_in[3];
  for (int i = 0; i < n_in; ++i) {
    switch (in_sizes[i]) {
      case 8192 * 1024: x = d_in[i]; break;
      case 1024 * 3072: Wqkv = d_in[i]; break;
      case 1024 * 1024: Wout = d_in[i]; break;
      case 1024:        bout = d_in[i]; break;
      default: break;
    }
  }

  char* ws = (char*)d_ws;
  short* qk    = (short*)(ws);                // 8192x2048 bf16 (q | k)   33.55 MB
  short* vT    = (short*)(ws + 33554432);     // 1024x8192 bf16           16.78 MB
  short* E     = (short*)(ws + 50331648);     // 2080 tiles of 128x128    68.16 MB
  short* xb    = (short*)(ws + 118489088);    // 8192x1024 bf16           16.78 MB
  short* attn  = xb;                          //   xb dead after GEMM1
  short* WqT   = (short*)(ws + 135266304);    // 3072x1024 bf16            6.29 MB
  short* WoT   = (short*)(ws + 141557760);    // 1024x1024 bf16            2.10 MB
  float* boutf = (float*)(ws + 143654912);    // 1024 fp32
  float* lsum  = (float*)(ws + 143659008);    // 8192 fp32 softmax denominators
  int*   flag  = (int*)  (ws + 143691776);    // dtype flag

  k_detect<<<1, 256, 0, stream>>>((const unsigned short*)x, flag);
  k_zerof<<<32, 256, 0, stream>>>(lsum, 8192);
  k_convert<<<1024, 256, 0, stream>>>(x, xb, 8192 * 1024, flag);
  k_to_f32<<<1, 256, 0, stream>>>(bout, boutf, 1024, flag);
  k_convT<<<dim3(96, 32), 256, 0, stream>>>(Wqkv, WqT, 1024, 3072, flag);
  k_convT<<<dim3(32, 32), 256, 0, stream>>>(Wout, WoT, 1024, 1024, flag);
  k_gemm_qkv<<<dim3(64, 24), 256, 0, stream>>>(xb, WqT, qk, vT);
  k_qk_exp<<<dim3(2080), 256, 0, stream>>>(qk, E, lsum);
  k_pv<<<dim3(32, 8), 512, 0, stream>>>(E, vT, lsum, attn);
  k_gemm_out<<<dim3(64, 8), 256, 0, stream>>>(attn, WoT, boutf, (float*)d_out);
}